// Round 1
// baseline (10141.727 us; speedup 1.0000x reference)
//
#include <hip/hip_runtime.h>
#include <hip/hip_bf16.h>

// ---------- helpers ----------
__device__ __forceinline__ unsigned ford(float f) {
    unsigned u = __float_as_uint(f);
    return (u & 0x80000000u) ? ~u : (u | 0x80000000u);
}
__device__ __forceinline__ float funord(unsigned u) {
    unsigned v = (u & 0x80000000u) ? (u & 0x7FFFFFFFu) : ~u;
    return __uint_as_float(v);
}
__device__ __forceinline__ float lrelu(float v) { return v > 0.f ? v : 0.2f * v; }

// ---------- SGEMM: C[M,N] = A[M,K] @ B[K,N], row-major ----------
template <int BM, int BN, int BK, int TM, int TN>
__launch_bounds__(256)
__global__ void sgemm_kernel(const float* __restrict__ A, const float* __restrict__ B,
                             float* __restrict__ C, int M, int N, int K) {
    __shared__ float As[BK][BM + 1];
    __shared__ float Bs[BK][BN + 1];
    const int bx = blockIdx.x;   // col tile
    const int by = blockIdx.y;   // row tile
    const int tid = threadIdx.x;
    constexpr int TCOLS = BN / TN;
    const int tc = tid % TCOLS;
    const int tr = tid / TCOLS;
    const int row0 = by * BM;
    float acc[TM][TN] = {};
    for (int k0 = 0; k0 < K; k0 += BK) {
        for (int i = tid; i < BM * BK; i += 256) {
            int r = i / BK, c = i % BK;
            int gr = row0 + r;
            As[c][r] = (gr < M) ? A[(size_t)gr * K + k0 + c] : 0.f;
        }
        for (int i = tid; i < BK * BN; i += 256) {
            int r = i / BN, c = i % BN;
            Bs[r][c] = B[(size_t)(k0 + r) * N + bx * BN + c];
        }
        __syncthreads();
#pragma unroll
        for (int k = 0; k < BK; k++) {
            float a[TM], b[TN];
#pragma unroll
            for (int i = 0; i < TM; i++) a[i] = As[k][tr * TM + i];
#pragma unroll
            for (int j = 0; j < TN; j++) b[j] = Bs[k][tc * TN + j];
#pragma unroll
            for (int i = 0; i < TM; i++)
#pragma unroll
                for (int j = 0; j < TN; j++) acc[i][j] += a[i] * b[j];
        }
        __syncthreads();
    }
    for (int i = 0; i < TM; i++) {
        int gr = row0 + tr * TM + i;
        if (gr >= M) continue;
        for (int j = 0; j < TN; j++)
            C[(size_t)gr * N + bx * BN + tc * TN + j] = acc[i][j];
    }
}

// ---------- layer-1 per-node scores: s[n,h] = sum_c h1[n,h,c]*a[h,c] ----------
__global__ void s1_kernel(const float* __restrict__ h1, const float* __restrict__ a_src,
                          const float* __restrict__ a_dst, float* __restrict__ s_src,
                          float* __restrict__ s_dst, int n) {
    int t = blockIdx.x * blockDim.x + threadIdx.x;
    if (t >= n * 8) return;
    int node = t >> 3, h = t & 7;
    const float4* hp = (const float4*)(h1 + (size_t)node * 128 + h * 16);
    const float4* ap = (const float4*)(a_src + h * 16);
    const float4* dp = (const float4*)(a_dst + h * 16);
    float ss = 0.f, sd = 0.f;
#pragma unroll
    for (int q = 0; q < 4; q++) {
        float4 hv = hp[q], av = ap[q], dv = dp[q];
        ss += hv.x * av.x + hv.y * av.y + hv.z * av.z + hv.w * av.w;
        sd += hv.x * dv.x + hv.y * dv.y + hv.z * dv.z + hv.w * dv.w;
    }
    s_src[t] = ss;
    s_dst[t] = sd;
}

// ---------- layer-1 edge passes ----------
__global__ void edge_max1(const int* __restrict__ ei, int E, int n,
                          const float* __restrict__ ssrc, const float* __restrict__ sdst,
                          unsigned* __restrict__ m) {
    int e = blockIdx.x * blockDim.x + threadIdx.x;
    int ET = E + n;
    if (e >= ET) return;
    int s, d;
    if (e < E) { s = ei[e]; d = ei[E + e]; } else { s = d = e - E; }
#pragma unroll
    for (int h = 0; h < 8; h++) {
        float v = lrelu(ssrc[s * 8 + h] + sdst[d * 8 + h]);
        atomicMax(&m[d * 8 + h], ford(v));
    }
}

__global__ void edge_sum1(const int* __restrict__ ei, int E, int n,
                          const float* __restrict__ ssrc, const float* __restrict__ sdst,
                          const unsigned* __restrict__ m, float* __restrict__ denom) {
    int e = blockIdx.x * blockDim.x + threadIdx.x;
    int ET = E + n;
    if (e >= ET) return;
    int s, d;
    if (e < E) { s = ei[e]; d = ei[E + e]; } else { s = d = e - E; }
#pragma unroll
    for (int h = 0; h < 8; h++) {
        float v = lrelu(ssrc[s * 8 + h] + sdst[d * 8 + h]);
        atomicAdd(&denom[d * 8 + h], expf(v - funord(m[d * 8 + h])));
    }
}

__global__ void edge_acc1(const int* __restrict__ ei, int E, int n,
                          const float* __restrict__ ssrc, const float* __restrict__ sdst,
                          const unsigned* __restrict__ m, const float* __restrict__ denom,
                          const float* __restrict__ h1, float* __restrict__ out1) {
    int t = blockIdx.x * blockDim.x + threadIdx.x;
    int ET = E + n;
    if (t >= ET * 8) return;
    int e = t >> 3, h = t & 7;
    int s, d;
    if (e < E) { s = ei[e]; d = ei[E + e]; } else { s = d = e - E; }
    float v = lrelu(ssrc[s * 8 + h] + sdst[d * 8 + h]);
    float alpha = expf(v - funord(m[d * 8 + h])) / denom[d * 8 + h];
    const float* hp = h1 + (size_t)s * 128 + h * 16;
    float* op = out1 + (size_t)d * 128 + h * 16;
#pragma unroll
    for (int c = 0; c < 16; c++) atomicAdd(&op[c], hp[c] * alpha);
}

// ---------- ELU(out1 + b1) in place ----------
__global__ void elu_bias(float* __restrict__ buf, const float* __restrict__ b, int total) {
    int i = blockIdx.x * blockDim.x + threadIdx.x;
    if (i >= total) return;
    float v = buf[i] + b[i & 127];
    buf[i] = v > 0.f ? v : (expf(v) - 1.f);
}

// ---------- layer-2 per-node scores (H=1, C=64) ----------
__global__ void s2_kernel(const float* __restrict__ h2, const float* __restrict__ a_src,
                          const float* __restrict__ a_dst, float* __restrict__ ssrc,
                          float* __restrict__ sdst, int n) {
    int node = blockIdx.x * blockDim.x + threadIdx.x;
    if (node >= n) return;
    const float4* hp = (const float4*)(h2 + (size_t)node * 64);
    float ss = 0.f, sd = 0.f;
#pragma unroll
    for (int q = 0; q < 16; q++) {
        float4 hv = hp[q];
        float4 av = ((const float4*)a_src)[q];
        float4 dv = ((const float4*)a_dst)[q];
        ss += hv.x * av.x + hv.y * av.y + hv.z * av.z + hv.w * av.w;
        sd += hv.x * dv.x + hv.y * dv.y + hv.z * dv.z + hv.w * dv.w;
    }
    ssrc[node] = ss;
    sdst[node] = sd;
}

// ---------- layer-2 edge passes (scalar head) ----------
__global__ void edge_max2(const int* __restrict__ ei, int E, int n,
                          const float* __restrict__ ssrc, const float* __restrict__ sdst,
                          unsigned* __restrict__ m) {
    int e = blockIdx.x * blockDim.x + threadIdx.x;
    int ET = E + n;
    if (e >= ET) return;
    int s, d;
    if (e < E) { s = ei[e]; d = ei[E + e]; } else { s = d = e - E; }
    float v = lrelu(ssrc[s] + sdst[d]);
    atomicMax(&m[d], ford(v));
}

__global__ void edge_sum2(const int* __restrict__ ei, int E, int n,
                          const float* __restrict__ ssrc, const float* __restrict__ sdst,
                          const unsigned* __restrict__ m, float* __restrict__ denom) {
    int e = blockIdx.x * blockDim.x + threadIdx.x;
    int ET = E + n;
    if (e >= ET) return;
    int s, d;
    if (e < E) { s = ei[e]; d = ei[E + e]; } else { s = d = e - E; }
    float v = lrelu(ssrc[s] + sdst[d]);
    atomicAdd(&denom[d], expf(v - funord(m[d])));
}

__global__ void edge_acc2(const int* __restrict__ ei, int E, int n,
                          const float* __restrict__ ssrc, const float* __restrict__ sdst,
                          const unsigned* __restrict__ m, const float* __restrict__ denom,
                          const float* __restrict__ h2, float* __restrict__ out2) {
    int t = blockIdx.x * blockDim.x + threadIdx.x;
    int ET = E + n;
    if (t >= ET * 4) return;
    int e = t >> 2, q = t & 3;
    int s, d;
    if (e < E) { s = ei[e]; d = ei[E + e]; } else { s = d = e - E; }
    float v = lrelu(ssrc[s] + sdst[d]);
    float alpha = expf(v - funord(m[d])) / denom[d];
    const float* hp = h2 + (size_t)s * 64 + q * 16;
    float* op = out2 + (size_t)d * 64 + q * 16;
#pragma unroll
    for (int c = 0; c < 16; c++) atomicAdd(&op[c], hp[c] * alpha);
}

// ---------- final: out = log_softmax(out2 + b2) per node over 64 ----------
__global__ void logsoftmax_kernel(const float* __restrict__ out2, const float* __restrict__ b2,
                                  float* __restrict__ out, int n) {
    int gid = blockIdx.x * blockDim.x + threadIdx.x;
    int node = gid >> 6;
    if (node >= n) return;
    int lane = gid & 63;
    float v = out2[(size_t)node * 64 + lane] + b2[lane];
    float mx = v;
#pragma unroll
    for (int off = 32; off; off >>= 1) mx = fmaxf(mx, __shfl_xor(mx, off, 64));
    float ex = expf(v - mx);
    float sum = ex;
#pragma unroll
    for (int off = 32; off; off >>= 1) sum += __shfl_xor(sum, off, 64);
    out[(size_t)node * 64 + lane] = v - mx - logf(sum);
}

extern "C" void kernel_launch(void* const* d_in, const int* in_sizes, int n_in,
                              void* d_out, int out_size, void* d_ws, size_t ws_size,
                              hipStream_t stream) {
    const float* x   = (const float*)d_in[0];
    const int*   ei  = (const int*)d_in[1];
    const float* W1  = (const float*)d_in[2];
    const float* a1s = (const float*)d_in[3];
    const float* a1d = (const float*)d_in[4];
    const float* b1  = (const float*)d_in[5];
    const float* W2  = (const float*)d_in[6];
    const float* a2s = (const float*)d_in[7];
    const float* a2d = (const float*)d_in[8];
    const float* b2  = (const float*)d_in[9];
    float* out = (float*)d_out;

    const int n = in_sizes[0] / 256;   // 50000
    const int E = in_sizes[1] / 2;     // 800000
    const int ET = E + n;

    // workspace layout (floats)
    float* ws = (float*)d_ws;
    float*    h1   = ws;                         // n*128
    float*    s1s  = h1 + (size_t)n * 128;       // n*8
    float*    s1d  = s1s + (size_t)n * 8;        // n*8
    unsigned* m1   = (unsigned*)(s1d + (size_t)n * 8);  // n*8
    float*    den1 = (float*)(m1 + (size_t)n * 8);      // n*8
    float*    out1 = den1 + (size_t)n * 8;       // n*128 (becomes h2in after ELU)
    float*    h2   = out1 + (size_t)n * 128;     // n*64
    float*    s2s  = h2 + (size_t)n * 64;        // n
    float*    s2d  = s2s + n;                    // n
    unsigned* m2   = (unsigned*)(s2d + n);       // n
    float*    den2 = (float*)(m2 + n);           // n
    float*    out2 = den2 + n;                   // n*64

    // init accumulators (ws is poisoned 0xAA before every call)
    hipMemsetAsync(m1, 0, (size_t)n * 8 * 4, stream);
    hipMemsetAsync(den1, 0, (size_t)n * 8 * 4, stream);
    hipMemsetAsync(out1, 0, (size_t)n * 128 * 4, stream);
    hipMemsetAsync(m2, 0, (size_t)n * 4, stream);
    hipMemsetAsync(den2, 0, (size_t)n * 4, stream);
    hipMemsetAsync(out2, 0, (size_t)n * 64 * 4, stream);

    const int B = 256;

    // layer 1
    {
        dim3 grid(128 / 64, (n + 63) / 64);
        sgemm_kernel<64, 64, 16, 4, 4><<<grid, 256, 0, stream>>>(x, W1, h1, n, 128, 256);
    }
    s1_kernel<<<(n * 8 + B - 1) / B, B, 0, stream>>>(h1, a1s, a1d, s1s, s1d, n);
    edge_max1<<<(ET + B - 1) / B, B, 0, stream>>>(ei, E, n, s1s, s1d, m1);
    edge_sum1<<<(ET + B - 1) / B, B, 0, stream>>>(ei, E, n, s1s, s1d, m1, den1);
    edge_acc1<<<((size_t)ET * 8 + B - 1) / B, B, 0, stream>>>(ei, E, n, s1s, s1d, m1, den1, h1, out1);
    elu_bias<<<((size_t)n * 128 + B - 1) / B, B, 0, stream>>>(out1, b1, n * 128);

    // layer 2
    {
        dim3 grid(64 / 64, (n + 63) / 64);
        sgemm_kernel<64, 64, 16, 4, 4><<<grid, 256, 0, stream>>>(out1, W2, h2, n, 64, 128);
    }
    s2_kernel<<<(n + B - 1) / B, B, 0, stream>>>(h2, a2s, a2d, s2s, s2d, n);
    edge_max2<<<(ET + B - 1) / B, B, 0, stream>>>(ei, E, n, s2s, s2d, m2);
    edge_sum2<<<(ET + B - 1) / B, B, 0, stream>>>(ei, E, n, s2s, s2d, m2, den2);
    edge_acc2<<<((size_t)ET * 4 + B - 1) / B, B, 0, stream>>>(ei, E, n, s2s, s2d, m2, den2, h2, out2);

    // epilogue
    logsoftmax_kernel<<<((size_t)n * 64 + B - 1) / B, B, 0, stream>>>(out2, b2, out, n);
}

// Round 2
// 603.925 us; speedup vs baseline: 16.7930x; 16.7930x over previous
//
#include <hip/hip_runtime.h>
#include <hip/hip_bf16.h>

__device__ __forceinline__ float lrelu(float v) { return v > 0.f ? v : 0.2f * v; }

// ---------- SGEMM: C[M,N] = A[M,K] @ B[K,N], row-major ----------
template <int BM, int BN, int BK, int TM, int TN>
__launch_bounds__(256)
__global__ void sgemm_kernel(const float* __restrict__ A, const float* __restrict__ B,
                             float* __restrict__ C, int M, int N, int K) {
    __shared__ float As[BK][BM + 1];
    __shared__ float Bs[BK][BN + 1];
    const int bx = blockIdx.x;
    const int by = blockIdx.y;
    const int tid = threadIdx.x;
    constexpr int TCOLS = BN / TN;
    const int tc = tid % TCOLS;
    const int tr = tid / TCOLS;
    const int row0 = by * BM;
    float acc[TM][TN] = {};
    for (int k0 = 0; k0 < K; k0 += BK) {
        for (int i = tid; i < BM * BK; i += 256) {
            int r = i / BK, c = i % BK;
            int gr = row0 + r;
            As[c][r] = (gr < M) ? A[(size_t)gr * K + k0 + c] : 0.f;
        }
        for (int i = tid; i < BK * BN; i += 256) {
            int r = i / BN, c = i % BN;
            Bs[r][c] = B[(size_t)(k0 + r) * N + bx * BN + c];
        }
        __syncthreads();
#pragma unroll
        for (int k = 0; k < BK; k++) {
            float a[TM], b[TN];
#pragma unroll
            for (int i = 0; i < TM; i++) a[i] = As[k][tr * TM + i];
#pragma unroll
            for (int j = 0; j < TN; j++) b[j] = Bs[k][tc * TN + j];
#pragma unroll
            for (int i = 0; i < TM; i++)
#pragma unroll
                for (int j = 0; j < TN; j++) acc[i][j] += a[i] * b[j];
        }
        __syncthreads();
    }
    for (int i = 0; i < TM; i++) {
        int gr = row0 + tr * TM + i;
        if (gr >= M) continue;
        for (int j = 0; j < TN; j++)
            C[(size_t)gr * N + bx * BN + tc * TN + j] = acc[i][j];
    }
}

// ---------- per-node scores layer 1: s[n,h] = sum_c h1[n,h,c]*a[h,c] ----------
__global__ void s1_kernel(const float* __restrict__ h1, const float* __restrict__ a_src,
                          const float* __restrict__ a_dst, float* __restrict__ s_src,
                          float* __restrict__ s_dst, int n) {
    int t = blockIdx.x * blockDim.x + threadIdx.x;
    if (t >= n * 8) return;
    int node = t >> 3, h = t & 7;
    const float4* hp = (const float4*)(h1 + (size_t)node * 128 + h * 16);
    const float4* ap = (const float4*)(a_src + h * 16);
    const float4* dp = (const float4*)(a_dst + h * 16);
    float ss = 0.f, sd = 0.f;
#pragma unroll
    for (int q = 0; q < 4; q++) {
        float4 hv = hp[q], av = ap[q], dv = dp[q];
        ss += hv.x * av.x + hv.y * av.y + hv.z * av.z + hv.w * av.w;
        sd += hv.x * dv.x + hv.y * dv.y + hv.z * dv.z + hv.w * dv.w;
    }
    s_src[t] = ss;
    s_dst[t] = sd;
}

// ---------- per-node scores layer 2 (H=1, C=64) ----------
__global__ void s2_kernel(const float* __restrict__ h2, const float* __restrict__ a_src,
                          const float* __restrict__ a_dst, float* __restrict__ ssrc,
                          float* __restrict__ sdst, int n) {
    int node = blockIdx.x * blockDim.x + threadIdx.x;
    if (node >= n) return;
    const float4* hp = (const float4*)(h2 + (size_t)node * 64);
    float ss = 0.f, sd = 0.f;
#pragma unroll
    for (int q = 0; q < 16; q++) {
        float4 hv = hp[q];
        float4 av = ((const float4*)a_src)[q];
        float4 dv = ((const float4*)a_dst)[q];
        ss += hv.x * av.x + hv.y * av.y + hv.z * av.z + hv.w * av.w;
        sd += hv.x * dv.x + hv.y * dv.y + hv.z * dv.z + hv.w * dv.w;
    }
    ssrc[node] = ss;
    sdst[node] = sd;
}

// ---------- CSR build: histogram, scan, scatter ----------
__global__ void hist_kernel(const int* __restrict__ ei, int E, int n, int* __restrict__ deg) {
    int e = blockIdx.x * blockDim.x + threadIdx.x;
    int ET = E + n;
    if (e >= ET) return;
    int d = (e < E) ? ei[E + e] : e - E;
    atomicAdd(&deg[d], 1);
}

__global__ void scan_kernel(const int* __restrict__ deg, int* __restrict__ rowptr, int n) {
    __shared__ int sdata[1024];
    __shared__ int carry;
    int tid = threadIdx.x;
    if (tid == 0) carry = 0;
    __syncthreads();
    for (int base = 0; base < n; base += 1024) {
        int i = base + tid;
        int v = (i < n) ? deg[i] : 0;
        sdata[tid] = v;
        __syncthreads();
        for (int off = 1; off < 1024; off <<= 1) {
            int t = (tid >= off) ? sdata[tid - off] : 0;
            __syncthreads();
            sdata[tid] += t;
            __syncthreads();
        }
        int incl = sdata[tid];
        int c = carry;
        if (i < n) rowptr[i] = c + incl - v;
        __syncthreads();
        if (tid == 0) carry = c + sdata[1023];
        __syncthreads();
    }
    if (tid == 0) rowptr[n] = carry;
}

__global__ void scatter_kernel(const int* __restrict__ ei, int E, int n,
                               int* __restrict__ cursor, int* __restrict__ csr_src) {
    int e = blockIdx.x * blockDim.x + threadIdx.x;
    int ET = E + n;
    if (e >= ET) return;
    int s, d;
    if (e < E) { s = ei[e]; d = ei[E + e]; } else { s = d = e - E; }
    int pos = atomicAdd(&cursor[d], 1);
    csr_src[pos] = s;
}

// ---------- layer-1 gather: one wave per dst node, online softmax ----------
// lane owns channels (lane) and (lane+64); head = c/16. Fuses bias+ELU.
__launch_bounds__(256)
__global__ void gather1_kernel(const int* __restrict__ rowptr, const int* __restrict__ csr_src,
                               const float* __restrict__ ssrc, const float* __restrict__ sdst,
                               const float* __restrict__ h1, const float* __restrict__ b1,
                               float* __restrict__ out1, int n) {
    int wid = blockIdx.x * 4 + (threadIdx.x >> 6);
    if (wid >= n) return;
    int lane = threadIdx.x & 63;
    int h0 = lane >> 4;                 // 0..3 ; second head = h0+4
    float sd0 = sdst[wid * 8 + h0];
    float sd1 = sdst[wid * 8 + h0 + 4];
    int beg = rowptr[wid], end = rowptr[wid + 1];
    float m0 = -INFINITY, m1 = -INFINITY;
    float d0 = 0.f, d1 = 0.f, a0 = 0.f, a1 = 0.f;
    for (int i = beg; i < end; i++) {
        int src = csr_src[i];
        float v0 = lrelu(ssrc[src * 8 + h0] + sd0);
        float v1 = lrelu(ssrc[src * 8 + h0 + 4] + sd1);
        float x0 = h1[(size_t)src * 128 + lane];
        float x1 = h1[(size_t)src * 128 + 64 + lane];
        float nm = fmaxf(m0, v0);
        float sc = __expf(m0 - nm);
        float e0 = __expf(v0 - nm);
        d0 = d0 * sc + e0; a0 = a0 * sc + e0 * x0; m0 = nm;
        nm = fmaxf(m1, v1);
        sc = __expf(m1 - nm);
        float e1 = __expf(v1 - nm);
        d1 = d1 * sc + e1; a1 = a1 * sc + e1 * x1; m1 = nm;
    }
    float o0 = a0 / d0 + b1[lane];
    float o1 = a1 / d1 + b1[64 + lane];
    out1[(size_t)wid * 128 + lane]      = o0 > 0.f ? o0 : (__expf(o0) - 1.f);
    out1[(size_t)wid * 128 + 64 + lane] = o1 > 0.f ? o1 : (__expf(o1) - 1.f);
}

// ---------- layer-2 gather + bias + log_softmax: one wave per node ----------
__launch_bounds__(256)
__global__ void gather2_kernel(const int* __restrict__ rowptr, const int* __restrict__ csr_src,
                               const float* __restrict__ ssrc, const float* __restrict__ sdst,
                               const float* __restrict__ h2, const float* __restrict__ b2,
                               float* __restrict__ out, int n) {
    int wid = blockIdx.x * 4 + (threadIdx.x >> 6);
    if (wid >= n) return;
    int lane = threadIdx.x & 63;
    float sd = sdst[wid];
    int beg = rowptr[wid], end = rowptr[wid + 1];
    float m = -INFINITY, den = 0.f, acc = 0.f;
    for (int i = beg; i < end; i++) {
        int src = csr_src[i];
        float v = lrelu(ssrc[src] + sd);
        float x = h2[(size_t)src * 64 + lane];
        float nm = fmaxf(m, v);
        float sc = __expf(m - nm);
        float e = __expf(v - nm);
        den = den * sc + e; acc = acc * sc + e * x; m = nm;
    }
    float o = acc / den + b2[lane];
    float mx = o;
#pragma unroll
    for (int off = 32; off; off >>= 1) mx = fmaxf(mx, __shfl_xor(mx, off, 64));
    float ex = __expf(o - mx);
    float sum = ex;
#pragma unroll
    for (int off = 32; off; off >>= 1) sum += __shfl_xor(sum, off, 64);
    out[(size_t)wid * 64 + lane] = o - mx - logf(sum);
}

extern "C" void kernel_launch(void* const* d_in, const int* in_sizes, int n_in,
                              void* d_out, int out_size, void* d_ws, size_t ws_size,
                              hipStream_t stream) {
    const float* x   = (const float*)d_in[0];
    const int*   ei  = (const int*)d_in[1];
    const float* W1  = (const float*)d_in[2];
    const float* a1s = (const float*)d_in[3];
    const float* a1d = (const float*)d_in[4];
    const float* b1  = (const float*)d_in[5];
    const float* W2  = (const float*)d_in[6];
    const float* a2s = (const float*)d_in[7];
    const float* a2d = (const float*)d_in[8];
    const float* b2  = (const float*)d_in[9];
    float* out = (float*)d_out;

    const int n = in_sizes[0] / 256;   // 50000
    const int E = in_sizes[1] / 2;     // 800000
    const int ET = E + n;

    // workspace layout
    float* ws = (float*)d_ws;
    float* h1   = ws;                          // n*128
    float* s1s  = h1 + (size_t)n * 128;        // n*8
    float* s1d  = s1s + (size_t)n * 8;         // n*8
    float* out1 = s1d + (size_t)n * 8;         // n*128
    float* h2   = out1 + (size_t)n * 128;      // n*64
    float* s2s  = h2 + (size_t)n * 64;         // n
    float* s2d  = s2s + n;                     // n
    int*   deg     = (int*)(s2d + n);          // n
    int*   rowptr  = deg + n;                  // n+1
    int*   cursor  = rowptr + n + 1;           // n
    int*   csr_src = cursor + n;               // ET

    hipMemsetAsync(deg, 0, (size_t)n * 4, stream);

    const int B = 256;

    // ---- CSR build (counting sort by dst) ----
    hist_kernel<<<(ET + B - 1) / B, B, 0, stream>>>(ei, E, n, deg);
    scan_kernel<<<1, 1024, 0, stream>>>(deg, rowptr, n);
    hipMemcpyAsync(cursor, rowptr, (size_t)n * 4, hipMemcpyDeviceToDevice, stream);
    scatter_kernel<<<(ET + B - 1) / B, B, 0, stream>>>(ei, E, n, cursor, csr_src);

    // ---- layer 1 ----
    {
        dim3 grid(128 / 64, (n + 63) / 64);
        sgemm_kernel<64, 64, 16, 4, 4><<<grid, 256, 0, stream>>>(x, W1, h1, n, 128, 256);
    }
    s1_kernel<<<(n * 8 + B - 1) / B, B, 0, stream>>>(h1, a1s, a1d, s1s, s1d, n);
    gather1_kernel<<<(n + 3) / 4, 256, 0, stream>>>(rowptr, csr_src, s1s, s1d, h1, b1, out1, n);

    // ---- layer 2 ----
    {
        dim3 grid(64 / 64, (n + 63) / 64);
        sgemm_kernel<64, 64, 16, 4, 4><<<grid, 256, 0, stream>>>(out1, W2, h2, n, 64, 128);
    }
    s2_kernel<<<(n + B - 1) / B, B, 0, stream>>>(h2, a2s, a2d, s2s, s2d, n);
    gather2_kernel<<<(n + 3) / 4, 256, 0, stream>>>(rowptr, csr_src, s2s, s2d, h2, b2, out, n);
}

// Round 3
// 444.229 us; speedup vs baseline: 22.8300x; 1.3595x over previous
//
#include <hip/hip_runtime.h>
#include <hip/hip_bf16.h>

typedef __attribute__((ext_vector_type(8))) short short8;
typedef __attribute__((ext_vector_type(4))) float f32x4;

__device__ __forceinline__ float lrelu(float v) { return v > 0.f ? v : 0.2f * v; }

__device__ __forceinline__ short bf16_hi(float f, float* back) {
    __hip_bfloat16 h = __float2bfloat16(f);
    *back = __bfloat162float(h);
    return __builtin_bit_cast(short, h);
}

// ---------- pack W[K][N] fp32 -> MFMA B-fragment order, hi/lo bf16 ----------
// frag idx: tile=(kt*NT+nt), lane, j ; element W[kt*32+(lane>>4)*8+j][nt*16+(lane&15)]
template <int K, int N>
__global__ void packW_kernel(const float* __restrict__ W, short* __restrict__ hi,
                             short* __restrict__ lo) {
    int t = blockIdx.x * blockDim.x + threadIdx.x;
    if (t >= K * N) return;
    constexpr int NT = N / 16;
    int j = t & 7, lane = (t >> 3) & 63, tile = t >> 9;
    int nt = tile % NT, kt = tile / NT;
    int k = kt * 32 + (lane >> 4) * 8 + j;
    int c = nt * 16 + (lane & 15);
    float w = W[(size_t)k * N + c];
    float back;
    hi[t] = bf16_hi(w, &back);
    float r;
    lo[t] = bf16_hi(w - back, &r);
}

// ---------- MFMA GEMM: C[M,N] = A[M,K] @ W[K,N], split-bf16 (3 passes) ----------
// One wave per 16 rows, full N width. No LDS, no barriers.
template <int K, int N>
__launch_bounds__(256)
__global__ void mfma_gemm(const float* __restrict__ A, const short* __restrict__ Bhi,
                          const short* __restrict__ Blo, float* __restrict__ C, int M) {
    constexpr int NT = N / 16, KT = K / 32;
    const int wave = threadIdx.x >> 6, lane = threadIdx.x & 63;
    const int row0 = (blockIdx.x * 4 + wave) * 16;
    if (row0 >= M) return;
    const int arow = row0 + (lane & 15);
    const float* ap = A + (size_t)arow * K + (lane >> 4) * 8;

    f32x4 acc[NT];
#pragma unroll
    for (int i = 0; i < NT; i++) acc[i] = (f32x4){0.f, 0.f, 0.f, 0.f};

    for (int kt = 0; kt < KT; kt++) {
        float av[8];
        *(float4*)(av)     = *(const float4*)(ap + kt * 32);
        *(float4*)(av + 4) = *(const float4*)(ap + kt * 32 + 4);
        short8 ahi, alo;
#pragma unroll
        for (int j = 0; j < 8; j++) {
            float back;
            ahi[j] = bf16_hi(av[j], &back);
            float r;
            alo[j] = bf16_hi(av[j] - back, &r);
        }
        const short8* bh = (const short8*)(Bhi + ((size_t)(kt * NT) * 64 + lane) * 8);
        const short8* bl = (const short8*)(Blo + ((size_t)(kt * NT) * 64 + lane) * 8);
#pragma unroll
        for (int nt = 0; nt < NT; nt++) {
            short8 bhv = bh[nt * 64];
            short8 blv = bl[nt * 64];
            acc[nt] = __builtin_amdgcn_mfma_f32_16x16x32_bf16(ahi, bhv, acc[nt], 0, 0, 0);
            acc[nt] = __builtin_amdgcn_mfma_f32_16x16x32_bf16(ahi, blv, acc[nt], 0, 0, 0);
            acc[nt] = __builtin_amdgcn_mfma_f32_16x16x32_bf16(alo, bhv, acc[nt], 0, 0, 0);
        }
    }
    // D layout: col = lane&15, row = (lane>>4)*4 + reg
    const int orow0 = row0 + (lane >> 4) * 4;
    const int col = lane & 15;
#pragma unroll
    for (int nt = 0; nt < NT; nt++)
#pragma unroll
        for (int r = 0; r < 4; r++) {
            int orow = orow0 + r;
            if (orow < M) C[(size_t)orow * N + nt * 16 + col] = acc[nt][r];
        }
}

// ---------- per-node scores layer 1 ----------
__global__ void s1_kernel(const float* __restrict__ h1, const float* __restrict__ a_src,
                          const float* __restrict__ a_dst, float* __restrict__ s_src,
                          float* __restrict__ s_dst, int n) {
    int t = blockIdx.x * blockDim.x + threadIdx.x;
    if (t >= n * 8) return;
    int node = t >> 3, h = t & 7;
    const float4* hp = (const float4*)(h1 + (size_t)node * 128 + h * 16);
    const float4* ap = (const float4*)(a_src + h * 16);
    const float4* dp = (const float4*)(a_dst + h * 16);
    float ss = 0.f, sd = 0.f;
#pragma unroll
    for (int q = 0; q < 4; q++) {
        float4 hv = hp[q], av = ap[q], dv = dp[q];
        ss += hv.x * av.x + hv.y * av.y + hv.z * av.z + hv.w * av.w;
        sd += hv.x * dv.x + hv.y * dv.y + hv.z * dv.z + hv.w * dv.w;
    }
    s_src[t] = ss;
    s_dst[t] = sd;
}

// ---------- per-node scores layer 2 ----------
__global__ void s2_kernel(const float* __restrict__ h2, const float* __restrict__ a_src,
                          const float* __restrict__ a_dst, float* __restrict__ ssrc,
                          float* __restrict__ sdst, int n) {
    int node = blockIdx.x * blockDim.x + threadIdx.x;
    if (node >= n) return;
    const float4* hp = (const float4*)(h2 + (size_t)node * 64);
    float ss = 0.f, sd = 0.f;
#pragma unroll
    for (int q = 0; q < 16; q++) {
        float4 hv = hp[q];
        float4 av = ((const float4*)a_src)[q];
        float4 dv = ((const float4*)a_dst)[q];
        ss += hv.x * av.x + hv.y * av.y + hv.z * av.z + hv.w * av.w;
        sd += hv.x * dv.x + hv.y * dv.y + hv.z * dv.z + hv.w * dv.w;
    }
    ssrc[node] = ss;
    sdst[node] = sd;
}

// ---------- CSR build ----------
__global__ void hist_kernel(const int* __restrict__ ei, int E, int n, int* __restrict__ deg) {
    int e = blockIdx.x * blockDim.x + threadIdx.x;
    int ET = E + n;
    if (e >= ET) return;
    int d = (e < E) ? ei[E + e] : e - E;
    atomicAdd(&deg[d], 1);
}

// hierarchical scan: per-block inclusive + block sums
__global__ void scan_block(const int* __restrict__ deg, int n, int* __restrict__ incl,
                           int* __restrict__ bsum) {
    __shared__ int wsum[16];
    int i = blockIdx.x * 1024 + threadIdx.x;
    int lane = threadIdx.x & 63, wv = threadIdx.x >> 6;
    int v = (i < n) ? deg[i] : 0;
    int s = v;
#pragma unroll
    for (int off = 1; off < 64; off <<= 1) {
        int t = __shfl_up(s, off, 64);
        if (lane >= off) s += t;
    }
    if (lane == 63) wsum[wv] = s;
    __syncthreads();
    if (wv == 0) {
        int w = (lane < 16) ? wsum[lane] : 0;
#pragma unroll
        for (int off = 1; off < 16; off <<= 1) {
            int t = __shfl_up(w, off, 64);
            if (lane >= off) w += t;
        }
        if (lane < 16) wsum[lane] = w;
    }
    __syncthreads();
    int add = wv ? wsum[wv - 1] : 0;
    if (i < n) incl[i] = s + add;
    if (threadIdx.x == 1023) bsum[blockIdx.x] = s + add;
}

// scan <=64 block sums -> exclusive offsets; boff[nb] = grand total
__global__ void scan_tops(const int* __restrict__ bsum, int nb, int* __restrict__ boff) {
    int lane = threadIdx.x;
    int v = (lane < nb) ? bsum[lane] : 0;
    int s = v;
#pragma unroll
    for (int off = 1; off < 64; off <<= 1) {
        int t = __shfl_up(s, off, 64);
        if (lane >= off) s += t;
    }
    if (lane < nb) boff[lane] = s - v;
    if (lane == 63) boff[nb] = s;
}

__global__ void scan_final(const int* __restrict__ incl, const int* __restrict__ deg,
                           const int* __restrict__ boff, int n, int nb,
                           int* __restrict__ rowptr) {
    int i = blockIdx.x * 1024 + threadIdx.x;
    if (i < n) rowptr[i] = boff[i >> 10] + incl[i] - deg[i];
    if (i == 0) rowptr[n] = boff[nb];
}

__global__ void scatter_kernel(const int* __restrict__ ei, int E, int n,
                               int* __restrict__ cursor, int* __restrict__ csr_src) {
    int e = blockIdx.x * blockDim.x + threadIdx.x;
    int ET = E + n;
    if (e >= ET) return;
    int s, d;
    if (e < E) { s = ei[e]; d = ei[E + e]; } else { s = d = e - E; }
    int pos = atomicAdd(&cursor[d], 1);
    csr_src[pos] = s;
}

// ---------- layer-1 gather: one wave per dst node, online softmax ----------
__launch_bounds__(256)
__global__ void gather1_kernel(const int* __restrict__ rowptr, const int* __restrict__ csr_src,
                               const float* __restrict__ ssrc, const float* __restrict__ sdst,
                               const float* __restrict__ h1, const float* __restrict__ b1,
                               float* __restrict__ out1, int n) {
    int wid = blockIdx.x * 4 + (threadIdx.x >> 6);
    if (wid >= n) return;
    int lane = threadIdx.x & 63;
    int h0 = lane >> 4;
    float sd0 = sdst[wid * 8 + h0];
    float sd1 = sdst[wid * 8 + h0 + 4];
    int beg = rowptr[wid], end = rowptr[wid + 1];
    float m0 = -INFINITY, m1 = -INFINITY;
    float d0 = 0.f, d1 = 0.f, a0 = 0.f, a1 = 0.f;
    for (int i = beg; i < end; i++) {
        int src = csr_src[i];
        float v0 = lrelu(ssrc[src * 8 + h0] + sd0);
        float v1 = lrelu(ssrc[src * 8 + h0 + 4] + sd1);
        float x0 = h1[(size_t)src * 128 + lane];
        float x1 = h1[(size_t)src * 128 + 64 + lane];
        float nm = fmaxf(m0, v0);
        float sc = __expf(m0 - nm);
        float e0 = __expf(v0 - nm);
        d0 = d0 * sc + e0; a0 = a0 * sc + e0 * x0; m0 = nm;
        nm = fmaxf(m1, v1);
        sc = __expf(m1 - nm);
        float e1 = __expf(v1 - nm);
        d1 = d1 * sc + e1; a1 = a1 * sc + e1 * x1; m1 = nm;
    }
    float o0 = a0 / d0 + b1[lane];
    float o1 = a1 / d1 + b1[64 + lane];
    out1[(size_t)wid * 128 + lane]      = o0 > 0.f ? o0 : (__expf(o0) - 1.f);
    out1[(size_t)wid * 128 + 64 + lane] = o1 > 0.f ? o1 : (__expf(o1) - 1.f);
}

// ---------- layer-2 gather + bias + log_softmax ----------
__launch_bounds__(256)
__global__ void gather2_kernel(const int* __restrict__ rowptr, const int* __restrict__ csr_src,
                               const float* __restrict__ ssrc, const float* __restrict__ sdst,
                               const float* __restrict__ h2, const float* __restrict__ b2,
                               float* __restrict__ out, int n) {
    int wid = blockIdx.x * 4 + (threadIdx.x >> 6);
    if (wid >= n) return;
    int lane = threadIdx.x & 63;
    float sd = sdst[wid];
    int beg = rowptr[wid], end = rowptr[wid + 1];
    float m = -INFINITY, den = 0.f, acc = 0.f;
    for (int i = beg; i < end; i++) {
        int src = csr_src[i];
        float v = lrelu(ssrc[src] + sd);
        float x = h2[(size_t)src * 64 + lane];
        float nm = fmaxf(m, v);
        float sc = __expf(m - nm);
        float e = __expf(v - nm);
        den = den * sc + e; acc = acc * sc + e * x; m = nm;
    }
    float o = acc / den + b2[lane];
    float mx = o;
#pragma unroll
    for (int off = 32; off; off >>= 1) mx = fmaxf(mx, __shfl_xor(mx, off, 64));
    float ex = __expf(o - mx);
    float sum = ex;
#pragma unroll
    for (int off = 32; off; off >>= 1) sum += __shfl_xor(sum, off, 64);
    out[(size_t)wid * 64 + lane] = o - mx - logf(sum);
}

extern "C" void kernel_launch(void* const* d_in, const int* in_sizes, int n_in,
                              void* d_out, int out_size, void* d_ws, size_t ws_size,
                              hipStream_t stream) {
    const float* x   = (const float*)d_in[0];
    const int*   ei  = (const int*)d_in[1];
    const float* W1  = (const float*)d_in[2];
    const float* a1s = (const float*)d_in[3];
    const float* a1d = (const float*)d_in[4];
    const float* b1  = (const float*)d_in[5];
    const float* W2  = (const float*)d_in[6];
    const float* a2s = (const float*)d_in[7];
    const float* a2d = (const float*)d_in[8];
    const float* b2  = (const float*)d_in[9];
    float* out = (float*)d_out;

    const int n = in_sizes[0] / 256;   // 50000
    const int E = in_sizes[1] / 2;     // 800000
    const int ET = E + n;
    const int NB = (n + 1023) / 1024;  // scan blocks (49)

    // workspace layout
    float* ws = (float*)d_ws;
    float* h1   = ws;                          // n*128
    float* s1s  = h1 + (size_t)n * 128;        // n*8
    float* s1d  = s1s + (size_t)n * 8;         // n*8
    float* out1 = s1d + (size_t)n * 8;         // n*128
    float* h2   = out1 + (size_t)n * 128;      // n*64
    float* s2s  = h2 + (size_t)n * 64;         // n
    float* s2d  = s2s + n;                     // n
    int*   deg     = (int*)(s2d + n);          // n
    int*   rowptr  = deg + n;                  // n+1
    int*   cursor  = rowptr + n + 1;           // n
    int*   csr_src = cursor + n;               // ET
    int*   incl    = csr_src + ET;             // n
    int*   bsum    = incl + n;                 // NB
    int*   boff    = bsum + NB;                // NB+1
    short* w1hi    = (short*)(boff + NB + 1);  // 256*128
    short* w1lo    = w1hi + 256 * 128;
    short* w2hi    = w1lo + 256 * 128;         // 128*64
    short* w2lo    = w2hi + 128 * 64;

    hipMemsetAsync(deg, 0, (size_t)n * 4, stream);

    const int B = 256;

    // ---- weight packing (tiny) ----
    packW_kernel<256, 128><<<(256 * 128 + B - 1) / B, B, 0, stream>>>(W1, w1hi, w1lo);
    packW_kernel<128, 64><<<(128 * 64 + B - 1) / B, B, 0, stream>>>(W2, w2hi, w2lo);

    // ---- CSR build (counting sort by dst) ----
    hist_kernel<<<(ET + B - 1) / B, B, 0, stream>>>(ei, E, n, deg);
    scan_block<<<NB, 1024, 0, stream>>>(deg, n, incl, bsum);
    scan_tops<<<1, 64, 0, stream>>>(bsum, NB, boff);
    scan_final<<<NB, 1024, 0, stream>>>(incl, deg, boff, n, NB, rowptr);
    hipMemcpyAsync(cursor, rowptr, (size_t)n * 4, hipMemcpyDeviceToDevice, stream);
    scatter_kernel<<<(ET + B - 1) / B, B, 0, stream>>>(ei, E, n, cursor, csr_src);

    // ---- layer 1 ----
    mfma_gemm<256, 128><<<(n + 63) / 64, 256, 0, stream>>>(x, w1hi, w1lo, h1, n);
    s1_kernel<<<(n * 8 + B - 1) / B, B, 0, stream>>>(h1, a1s, a1d, s1s, s1d, n);
    gather1_kernel<<<(n + 3) / 4, 256, 0, stream>>>(rowptr, csr_src, s1s, s1d, h1, b1, out1, n);

    // ---- layer 2 ----
    mfma_gemm<128, 64><<<(n + 63) / 64, 256, 0, stream>>>(out1, w2hi, w2lo, h2, n);
    s2_kernel<<<(n + B - 1) / B, B, 0, stream>>>(h2, a2s, a2d, s2s, s2d, n);
    gather2_kernel<<<(n + 3) / 4, 256, 0, stream>>>(rowptr, csr_src, s2s, s2d, h2, b2, out, n);
}